// Round 2
// baseline (383.874 us; speedup 1.0000x reference)
//
#include <hip/hip_runtime.h>

// MotherCubeConv: out[n,:] = concat(features[n,:], prev[idx[n,0..3],:]) @ W^T + b
// Gathered GEMM [200000 x 640] x [640 x 128] via bf16 MFMA, 3-term hi/lo split:
//   A*W ~= A_hi*W_hi + A_lo*W_hi + A_hi*W_lo   (error ~1e-5 absmax)
// No LDS / no barriers: each wave owns 64 rows (2 m-tiles of 32x32x16 MFMA),
// A loaded direct from global (2 lanes cover one 512B row), W fragments
// precomputed fragment-ready (bf16 hi/lo) in d_ws by a tiny pre-kernel.
// All bf16 handling is integer bit-ops (no __hip_bfloat16 types -> no
// bit_cast-of-non-trivially-copyable compile error).

#define N_PTS  200000
#define F_INN  128
#define K_TOT  640      // 5 * F_IN
#define NCHUNK 40       // K_TOT / 16
#define NCT    4        // 128 cols / 32

typedef __attribute__((ext_vector_type(8)))  short bf16x8;   // MFMA A/B operand (8 bf16)
typedef __attribute__((ext_vector_type(16))) float f32x16;   // MFMA C/D (32x32)
typedef __attribute__((ext_vector_type(8)))  float f32x8;

union Frag { bf16x8 v; unsigned int u[4]; };

__device__ __forceinline__ unsigned int bf_rne_bits(float f) {
    unsigned int u = __builtin_bit_cast(unsigned int, f);
    return (u + 0x7FFFu + ((u >> 16) & 1u)) & 0xFFFF0000u;  // fp32 bits of RNE-bf16
}

// RNE split (used for W only — runs once per launch over 80 KB)
__device__ __forceinline__ void split8_rne(const f32x8 a, bf16x8& hi, bf16x8& lo) {
    Frag H, L;
#pragma unroll
    for (int p = 0; p < 4; ++p) {
        float f0 = a[2 * p], f1 = a[2 * p + 1];
        unsigned int h0 = bf_rne_bits(f0), h1 = bf_rne_bits(f1);
        float r0 = f0 - __builtin_bit_cast(float, h0);
        float r1 = f1 - __builtin_bit_cast(float, h1);
        unsigned int l0 = bf_rne_bits(r0), l1 = bf_rne_bits(r1);
        H.u[p] = (h0 >> 16) | h1;
        L.u[p] = (l0 >> 16) | l1;
    }
    hi = H.v; lo = L.v;
}

// Truncation split (hot path, A operand): hi=trunc(f), lo=trunc(f-hi).
// hi's trunc error is captured exactly by the residual; lo trunc error ~2^-16 rel.
__device__ __forceinline__ void split8_trunc(const f32x8 a, bf16x8& hi, bf16x8& lo) {
    Frag H, L;
#pragma unroll
    for (int p = 0; p < 4; ++p) {
        float f0 = a[2 * p], f1 = a[2 * p + 1];
        unsigned int u0 = __builtin_bit_cast(unsigned int, f0);
        unsigned int u1 = __builtin_bit_cast(unsigned int, f1);
        unsigned int h0 = u0 & 0xFFFF0000u, h1 = u1 & 0xFFFF0000u;
        float r0 = f0 - __builtin_bit_cast(float, h0);
        float r1 = f1 - __builtin_bit_cast(float, h1);
        unsigned int l0 = __builtin_bit_cast(unsigned int, r0);
        unsigned int l1 = __builtin_bit_cast(unsigned int, r1);
        H.u[p] = (h0 >> 16) | h1;
        L.u[p] = (l0 >> 16) | (l1 & 0xFFFF0000u);
    }
    hi = H.v; lo = L.v;
}

// Pre-kernel: W [128 x 640] fp32 -> fragment-ready bf16 hi/lo arrays.
// wf[(t*4+ct)*64 + lane][j] = W[c][k],  c = ct*32+(lane&31), k = t*16+(lane>>5)*8+j
// (canonical verified k-map: k = k0 + (lane>>5)*8 + j, same as A operand)
__global__ void build_wf(const float* __restrict__ W,
                         bf16x8* __restrict__ wf_hi,
                         bf16x8* __restrict__ wf_lo) {
    int tid = blockIdx.x * blockDim.x + threadIdx.x;  // (t*4+ct)*64 + lane
    int lane = tid & 63;
    int ct   = (tid >> 6) & 3;
    int t    = tid >> 8;
    if (t >= NCHUNK) return;
    int c = ct * 32 + (lane & 31);
    int k = t * 16 + (lane >> 5) * 8;
    f32x8 w = *(const f32x8*)(W + (size_t)c * K_TOT + k);
    bf16x8 h, l;
    split8_rne(w, h, l);
    wf_hi[tid] = h;
    wf_lo[tid] = l;
}

__global__ __launch_bounds__(256, 2)
void mcconv(const float* __restrict__ feat, const float* __restrict__ prev,
            const int* __restrict__ nbr, const float* __restrict__ bias,
            const bf16x8* __restrict__ wf_hi, const bf16x8* __restrict__ wf_lo,
            float* __restrict__ out) {
    const int lane = threadIdx.x & 63;
    const int wave = threadIdx.x >> 6;
    const int g    = lane >> 5;     // half-wave: which 8-of-16 k values
    const int r31  = lane & 31;
    const int n0   = blockIdx.x * 256 + wave * 64;   // wave's first row

    // two m-tiles of 32 rows; lanes l and l+32 share a row (cover 2 k-halves)
    int nA = n0 + r31;
    int nB = n0 + 32 + r31;
    int nAc = nA < N_PTS ? nA : N_PTS - 1;
    int nBc = nB < N_PTS ? nB : N_PTS - 1;

    const int4 iA = *(const int4*)(nbr + 4 * (size_t)nAc);
    const int4 iB = *(const int4*)(nbr + 4 * (size_t)nBc);

    f32x16 acc[2][NCT];
#pragma unroll
    for (int m = 0; m < 2; ++m)
#pragma unroll
        for (int c = 0; c < NCT; ++c)
#pragma unroll
            for (int i = 0; i < 16; ++i) acc[m][c][i] = 0.0f;

    // K loop: 5 segments (self + 4 neighbors) x 8 chunks of k=16
    for (int s = 0; s < 5; ++s) {
        const float* pA;
        const float* pB;
        if (s == 0)      { pA = feat + (size_t)nAc * F_INN;  pB = feat + (size_t)nBc * F_INN; }
        else if (s == 1) { pA = prev + (size_t)iA.x * F_INN; pB = prev + (size_t)iB.x * F_INN; }
        else if (s == 2) { pA = prev + (size_t)iA.y * F_INN; pB = prev + (size_t)iB.y * F_INN; }
        else if (s == 3) { pA = prev + (size_t)iA.z * F_INN; pB = prev + (size_t)iB.z * F_INN; }
        else             { pA = prev + (size_t)iA.w * F_INN; pB = prev + (size_t)iB.w * F_INN; }

#pragma unroll
        for (int cc = 0; cc < 8; ++cc) {
            const int t = s * 8 + cc;
            f32x8 a0 = *(const f32x8*)(pA + cc * 16 + g * 8);
            f32x8 a1 = *(const f32x8*)(pB + cc * 16 + g * 8);

            bf16x8 bh[NCT], bl[NCT];
#pragma unroll
            for (int ct = 0; ct < NCT; ++ct) {
                int fi = (t * 4 + ct) * 64 + lane;
                bh[ct] = wf_hi[fi];
                bl[ct] = wf_lo[fi];
            }

            bf16x8 a0h, a0l, a1h, a1l;
            split8_trunc(a0, a0h, a0l);
            split8_trunc(a1, a1h, a1l);

#pragma unroll
            for (int ct = 0; ct < NCT; ++ct) {
                acc[0][ct] = __builtin_amdgcn_mfma_f32_32x32x16_bf16(a0h, bh[ct], acc[0][ct], 0, 0, 0);
                acc[0][ct] = __builtin_amdgcn_mfma_f32_32x32x16_bf16(a0l, bh[ct], acc[0][ct], 0, 0, 0);
                acc[0][ct] = __builtin_amdgcn_mfma_f32_32x32x16_bf16(a0h, bl[ct], acc[0][ct], 0, 0, 0);
                acc[1][ct] = __builtin_amdgcn_mfma_f32_32x32x16_bf16(a1h, bh[ct], acc[1][ct], 0, 0, 0);
                acc[1][ct] = __builtin_amdgcn_mfma_f32_32x32x16_bf16(a1l, bh[ct], acc[1][ct], 0, 0, 0);
                acc[1][ct] = __builtin_amdgcn_mfma_f32_32x32x16_bf16(a1h, bl[ct], acc[1][ct], 0, 0, 0);
            }
        }
    }

    // epilogue: bias + store. C/D layout (m74/m101): col = lane&31,
    // row = (reg&3) + 8*(reg>>2) + 4*(lane>>5)
    float bcol[NCT];
#pragma unroll
    for (int ct = 0; ct < NCT; ++ct) bcol[ct] = bias[ct * 32 + r31];

#pragma unroll
    for (int m = 0; m < 2; ++m) {
        const int nbase = n0 + m * 32 + 4 * g;
#pragma unroll
        for (int reg = 0; reg < 16; ++reg) {
            const int row = nbase + (reg & 3) + 8 * (reg >> 2);
            if (row < N_PTS) {
#pragma unroll
                for (int ct = 0; ct < NCT; ++ct)
                    out[(size_t)row * F_INN + ct * 32 + r31] = acc[m][ct][reg] + bcol[ct];
            }
        }
    }
}

extern "C" void kernel_launch(void* const* d_in, const int* in_sizes, int n_in,
                              void* d_out, int out_size, void* d_ws, size_t ws_size,
                              hipStream_t stream) {
    const float* feat = (const float*)d_in[0];
    const float* prev = (const float*)d_in[1];
    const int*   nbr  = (const int*)d_in[2];
    const float* W    = (const float*)d_in[3];
    const float* bias = (const float*)d_in[4];
    float* out = (float*)d_out;

    // workspace: wf_hi (160 KiB) + wf_lo (160 KiB)
    bf16x8* wf_hi = (bf16x8*)d_ws;
    bf16x8* wf_lo = (bf16x8*)((char*)d_ws + (size_t)NCHUNK * NCT * 64 * sizeof(bf16x8));

    hipLaunchKernelGGL(build_wf, dim3(NCHUNK), dim3(256), 0, stream, W, wf_hi, wf_lo);

    const int grid = (N_PTS + 255) / 256;   // 782 blocks, 4 waves x 64 rows each
    hipLaunchKernelGGL(mcconv, dim3(grid), dim3(256), 0, stream,
                       feat, prev, nbr, bias, wf_hi, wf_lo, out);
}